// Round 3
// baseline (793.878 us; speedup 1.0000x reference)
//
#include <hip/hip_runtime.h>

// ---------------- constants ----------------
#define Bk 32      // batch
#define Nn 128     // nodes
#define Cc 128     // in channels
#define BN_EPS 1e-5f
#define GRIDN 512  // persistent grid: 2 blocks/CU on 256 CUs (co-residency guaranteed
                   // by __launch_bounds__(256,2): VGPR<=256, LDS union 17.7KB)

typedef __attribute__((ext_vector_type(8))) short short8;
typedef __attribute__((ext_vector_type(4))) float floatx4;

// workspace offsets (floats)
#define OFF_UV   ((size_t)0)         // 524288  uv f32 [4096][128]
#define OFF_AP   ((size_t)524288)    // 524288  masked exp scores (upper-tri valid, rest zeroed)
#define OFF_LB   ((size_t)1048576)   // 524288 f = bf16 L [2 rel][32 b][128][128]
#define OFF_H0   ((size_t)1572864)   // 262144
#define OFF_H1   ((size_t)1835008)   // 1048576
#define OFF_WC   ((size_t)2899968)   // 5120
#define OFF_BC   ((size_t)2905088)   // 16
#define OFF_XB0  ((size_t)2905104)   // 262144 f = bf16 x
#define OFF_XB   ((size_t)3167248)   // 3145728 f = bf16 Xcat [4096][1536max]
#define OFF_WT   ((size_t)6312976)   // 475136 f (Wt0,Wt1,Wt2,Wuv)
#define WUV_OFS  933888              // ushort offset of Wuv inside WT region

__device__ __forceinline__ unsigned short f2b(float f) {
    unsigned int x = __float_as_uint(f);
    unsigned int r = x + 0x7FFFu + ((x >> 16) & 1u);
    return (unsigned short)(r >> 16);
}

// ---------------- LDS union: max member = edge (17.7 KB) ----------------
union __align__(16) SMem {
    struct { unsigned short Ts[64][65]; } prep;                                  //  8.3 KB
    struct { unsigned short As[128 * 40]; unsigned short Bs[64 * 40]; } uv;      // 15.4 KB
    struct { float ui[16][68]; float vi[16][68];
             float uj[16][68]; float vj[16][68]; float w2[64]; } edge;           // 17.7 KB
    struct { float part[256]; float invS[128]; float t1S[128]; float Dv[128]; } adj; // 2.5 KB
    struct { unsigned short XsT[32 * 136]; unsigned short T1T[32 * 136]; } cheb; // 17.4 KB
    struct { unsigned short As[2 * 64 * 40]; unsigned short Bs[64 * 40];
             float wmax[4][64]; } fc;                                            // 16.4 KB
};

// ---------------- device-wide barrier (sense-reversing, agent scope) ----------------
__device__ unsigned g_cnt = 0;
__device__ unsigned g_gen = 0;

__device__ __forceinline__ void gsync() {
    __syncthreads();
    if (threadIdx.x == 0) {
        __threadfence();   // release this block's phase writes (L2 writeback)
        unsigned gen = __hip_atomic_load(&g_gen, __ATOMIC_RELAXED, __HIP_MEMORY_SCOPE_AGENT);
        unsigned arr = __hip_atomic_fetch_add(&g_cnt, 1u, __ATOMIC_ACQ_REL, __HIP_MEMORY_SCOPE_AGENT) + 1u;
        if (arr == (unsigned)GRIDN) {
            __hip_atomic_store(&g_cnt, 0u, __ATOMIC_RELAXED, __HIP_MEMORY_SCOPE_AGENT);
            __hip_atomic_fetch_add(&g_gen, 1u, __ATOMIC_ACQ_REL, __HIP_MEMORY_SCOPE_AGENT);
        } else {
            while (__hip_atomic_load(&g_gen, __ATOMIC_RELAXED, __HIP_MEMORY_SCOPE_AGENT) == gen)
                __builtin_amdgcn_s_sleep(2);
        }
        __threadfence();   // acquire: invalidate stale cache before reading other XCDs' writes
    }
    __syncthreads();
}

// ---------------- args ----------------
struct MArgs {
    const float *x, *A, *mask, *eW1, *eb1, *eW2, *eb2;
    const float *W0, *W1, *W2;
    const float *gb0, *gg0, *gB0, *gm0, *gv0;
    const float *gb1, *gg1, *gB1, *gm1, *gv1;
    const float *gb2, *gg2, *gB2, *gm2, *gv2;
    const float *fW1, *fb1, *fW2, *fb2;
    float *uv, *ap, *h0, *h1, *Wc, *bc;
    unsigned short *Lb, *xb0, *Xb, *Wt;
    float *outc;
};

// ---------------- P0: weight transposes, Wuv, folded classifier, x->bf16, ap zero ----------------
__device__ __forceinline__ void st_prep(SMem& sm, int vb, int tid, const MArgs& a) {
    if (vb < 228) {
        const float* src; unsigned short* dst; int N, ldK, k0, n0;
        if (vb < 12)      { src = a.W0; dst = a.Wt;          N = 64;  ldK = 768;  k0 = vb * 64;       n0 = 0; }
        else if (vb < 36) { int t = vb - 12; src = a.W1; dst = a.Wt + 49152;  N = 256; ldK = 384;  k0 = (t % 6) * 64;  n0 = (t / 6) * 64; }
        else              { int t = vb - 36; src = a.W2; dst = a.Wt + 147456; N = 512; ldK = 1536; k0 = (t % 24) * 64; n0 = (t / 24) * 64; }
#pragma unroll
        for (int p = 0; p < 16; ++p) {
            int e = tid + p * 256; int r = e >> 6, c = e & 63;
            sm.prep.Ts[r][c] = f2b(src[(size_t)(k0 + r) * N + n0 + c]);
        }
        __syncthreads();
#pragma unroll
        for (int p = 0; p < 16; ++p) {
            int e = tid + p * 256; int n = e >> 6, k = e & 63;
            dst[(size_t)(n0 + n) * ldK + k0 + k] = sm.prep.Ts[k][n];
        }
    } else if (vb < 232) {
        int tt = vb - 228;
        int half = tt >> 1, kt = tt & 1;
        int k0 = kt * 64;
        unsigned short* Wuv = a.Wt + WUV_OFS;
#pragma unroll
        for (int p = 0; p < 16; ++p) {
            int e = tid + p * 256; int r = e >> 6, c = e & 63;
            sm.prep.Ts[r][c] = f2b(a.eW1[(size_t)(half * 128 + k0 + r) * 64 + c]);
        }
        __syncthreads();
#pragma unroll
        for (int p = 0; p < 16; ++p) {
            int e = tid + p * 256; int n = e >> 6, k = e & 63;
            Wuv[(size_t)(half * 64 + n) * 128 + k0 + k] = sm.prep.Ts[k][n];
        }
    } else if (vb < 253) {
        int e = (vb - 232) * 256 + tid;
        if (e < 5120) {
            int i = e / 10, j = e - i * 10;
            float acc = 0.f;
            for (int h = 0; h < 256; ++h) acc += a.fW1[(size_t)i * 256 + h] * a.fW2[(size_t)h * 10 + j];
            a.Wc[e] = acc;
        } else if (e < 5130) {
            int j = e - 5120;
            float acc = a.fb2[j];
            for (int h = 0; h < 256; ++h) acc += a.fb1[h] * a.fW2[(size_t)h * 10 + j];
            a.bc[j] = acc;
        }
    } else if (vb < 765) {
        int idx = (vb - 253) * 256 + tid;
        float4 vv = ((const float4*)a.x)[idx];
        ushort4 o;
        o.x = f2b(vv.x); o.y = f2b(vv.y); o.z = f2b(vv.z); o.w = f2b(vv.w);
        ((ushort4*)a.xb0)[idx] = o;
    } else {
        // zero ap for batch (vb-765): edge phase only writes strict upper-tri
        int b = vb - 765;
        float4* dst = (float4*)(a.ap + (size_t)b * Nn * Nn);
        float4 z4 = {0.f, 0.f, 0.f, 0.f};
#pragma unroll
        for (int i = 0; i < 16; ++i) dst[tid + i * 256] = z4;
    }
}

// ---------------- P1a: uv = x @ Wuv (+eb1 on u cols) via bf16 MFMA ----------------
__device__ __forceinline__ void st_uv(SMem& sm, int tid, int bx, int by,
                                      const unsigned short* __restrict__ xb0,
                                      const unsigned short* __restrict__ Wuv,
                                      const float* __restrict__ eb1,
                                      float* __restrict__ uv) {
    unsigned short* As = sm.uv.As;
    unsigned short* Bs = sm.uv.Bs;
    int w = tid >> 6, lane = tid & 63, quad = lane >> 4, lr = lane & 15;
    int row0 = by * 128, col0 = bx * 64;
    floatx4 acc[2][4];
#pragma unroll
    for (int rt = 0; rt < 2; ++rt)
#pragma unroll
        for (int ct = 0; ct < 4; ++ct) acc[rt][ct] = (floatx4){0.f, 0.f, 0.f, 0.f};
    int arow[2], asub[2];
#pragma unroll
    for (int i = 0; i < 2; ++i) { int ch = tid + i * 256; arow[i] = ch >> 2; asub[i] = ch & 3; }
    int brow = tid >> 2, bsub = tid & 3;
    for (int k0 = 0; k0 < 128; k0 += 32) {
        short8 ra[2];
#pragma unroll
        for (int i = 0; i < 2; ++i)
            ra[i] = *(const short8*)(xb0 + (size_t)(row0 + arow[i]) * 128 + k0 + asub[i] * 8);
        short8 rb = *(const short8*)(Wuv + (size_t)(col0 + brow) * 128 + k0 + bsub * 8);
        __syncthreads();
#pragma unroll
        for (int i = 0; i < 2; ++i) *(short8*)&As[arow[i] * 40 + asub[i] * 8] = ra[i];
        *(short8*)&Bs[brow * 40 + bsub * 8] = rb;
        __syncthreads();
        short8 av[2], bv[4];
#pragma unroll
        for (int rt = 0; rt < 2; ++rt)
            av[rt] = *(const short8*)&As[(w * 32 + rt * 16 + lr) * 40 + quad * 8];
#pragma unroll
        for (int ct = 0; ct < 4; ++ct)
            bv[ct] = *(const short8*)&Bs[(ct * 16 + lr) * 40 + quad * 8];
#pragma unroll
        for (int rt = 0; rt < 2; ++rt)
#pragma unroll
            for (int ct = 0; ct < 4; ++ct)
                acc[rt][ct] = __builtin_amdgcn_mfma_f32_16x16x32_bf16(av[rt], bv[ct], acc[rt][ct], 0, 0, 0);
    }
#pragma unroll
    for (int rt = 0; rt < 2; ++rt) {
        int rbase = row0 + w * 32 + rt * 16 + quad * 4;
#pragma unroll
        for (int ct = 0; ct < 4; ++ct) {
            int col = col0 + ct * 16 + lr;
            float bi = (col < 64) ? eb1[col] : 0.f;
#pragma unroll
            for (int reg = 0; reg < 4; ++reg)
                uv[(size_t)(rbase + reg) * 128 + col] = acc[rt][ct][reg] + bi;
        }
    }
}

// ---------------- P1b: A-path Laplacian (rel0) ----------------
__device__ __forceinline__ void st_adjA(SMem& sm, int tid, int b,
                                        const float* __restrict__ A,
                                        unsigned short* __restrict__ Lb) {
    const float* Ar = A + (size_t)b * Nn * Nn;
    int j = tid & 127, half = tid >> 7;
    float sum = 0.f;
    for (int i = half * 64; i < half * 64 + 64; ++i) sum += Ar[i * Nn + j];
    sm.adj.part[tid] = sum;
    __syncthreads();
    if (tid < 128) sm.adj.Dv[tid] = rsqrtf(sm.adj.part[tid] + sm.adj.part[tid + 128] + 1e-5f);
    __syncthreads();
    unsigned short* Lo = Lb + (size_t)b * Nn * Nn;
    for (int k = 0; k < 64; ++k) {
        int idx = tid + k * 256;
        int i = idx >> 7, jj = idx & 127;
        Lo[idx] = f2b(sm.adj.Dv[i] * Ar[idx] * sm.adj.Dv[jj]);
    }
}

// ---------------- P2a: symmetric masked-exp edge scores (upper-tri tile pairs) ----------------
__device__ __forceinline__ void st_edge(SMem& sm, int tid, int t, int b,
                                        const float* __restrict__ uv,
                                        const float* __restrict__ eW2,
                                        const float* __restrict__ eb2,
                                        const float* __restrict__ mask,
                                        float* __restrict__ ap) {
    int ti = 0, rem = t;
    for (;;) { int w = 8 - ti; if (rem < w) break; rem -= w; ++ti; }
    int tj = ti + rem;
    int i0 = ti * 16, j0 = tj * 16;
    int r = tid >> 4, c4 = (tid & 15) * 4;
    const float* uvb = uv + (size_t)b * Nn * 128;
    *(float4*)&sm.edge.ui[r][c4] = *(const float4*)(uvb + (size_t)(i0 + r) * 128 + c4);
    *(float4*)&sm.edge.vi[r][c4] = *(const float4*)(uvb + (size_t)(i0 + r) * 128 + 64 + c4);
    *(float4*)&sm.edge.uj[r][c4] = *(const float4*)(uvb + (size_t)(j0 + r) * 128 + c4);
    *(float4*)&sm.edge.vj[r][c4] = *(const float4*)(uvb + (size_t)(j0 + r) * 128 + 64 + c4);
    if (tid < 64) sm.edge.w2[tid] = eW2[tid];
    __syncthreads();
    int il = tid >> 4, jl = tid & 15;
    int gi = i0 + il, gj = j0 + jl;
    if (gj > gi) {
        float d = 0.f;
#pragma unroll
        for (int h4 = 0; h4 < 16; ++h4) {
            float4 a1 = *(const float4*)&sm.edge.ui[il][h4 * 4];
            float4 b1 = *(const float4*)&sm.edge.vj[jl][h4 * 4];
            float4 a2 = *(const float4*)&sm.edge.uj[jl][h4 * 4];
            float4 b2 = *(const float4*)&sm.edge.vi[il][h4 * 4];
            float4 ww = *(const float4*)&sm.edge.w2[h4 * 4];
            d += (fmaxf(a1.x + b1.x, 0.f) + fmaxf(a2.x + b2.x, 0.f)) * ww.x
               + (fmaxf(a1.y + b1.y, 0.f) + fmaxf(a2.y + b2.y, 0.f)) * ww.y
               + (fmaxf(a1.z + b1.z, 0.f) + fmaxf(a2.z + b2.z, 0.f)) * ww.z
               + (fmaxf(a1.w + b1.w, 0.f) + fmaxf(a2.w + b2.w, 0.f)) * ww.w;
        }
        float p = 0.5f * d + eb2[0];
        float mi = mask[b * Nn + gi], mj = mask[b * Nn + gj];
        float val = (mi != 0.f && mj != 0.f) ? expf(fminf(p, 80.f)) : 0.f;
        ap[((size_t)(b * Nn + gi)) * Nn + gj] = val;
    }
}

// ---------------- P3: An-path Laplacian (rel1), global-ap version (2.5 KB LDS) ----------------
__device__ __forceinline__ void st_adjAn(SMem& sm, int tid, int b,
                                         const float* __restrict__ ap,
                                         unsigned short* __restrict__ Lb) {
    const float* apg = ap + (size_t)b * Nn * Nn;
    {   // row sums (ap is zero on diag/lower, so full-row sum == upper-row sum)
        int row = tid >> 1, half = tid & 1;
        const float* rp = apg + (size_t)row * Nn + half * 64;
        float s0 = 0.f;
        for (int jj = 0; jj < 64; jj += 4) {
            float4 v = *(const float4*)(rp + jj);
            s0 += v.x; s0 += v.y; s0 += v.z; s0 += v.w;
        }
        sm.adj.part[tid] = s0;
    }
    __syncthreads();
    if (tid < 128) {
        float rsum = sm.adj.part[tid * 2] + sm.adj.part[tid * 2 + 1];
        sm.adj.invS[tid] = (rsum == 0.f) ? 1.f : (1.f / rsum);
        sm.adj.t1S[tid]  = (rsum == 0.f) ? 0.f : 1.f;
    }
    __syncthreads();
    {   // column sums of ap*invS (coalesced across lanes per j)
        int col = tid >> 1, half = tid & 1;
        float s0 = 0.f;
        for (int jj = half * 64; jj < half * 64 + 64; ++jj)
            s0 += apg[(size_t)jj * Nn + col] * sm.adj.invS[jj];
        sm.adj.part[tid] = s0;
    }
    __syncthreads();
    if (tid < 128)
        sm.adj.Dv[tid] = rsqrtf(sm.adj.t1S[tid] + sm.adj.part[tid * 2] + sm.adj.part[tid * 2 + 1] + 1e-5f);
    __syncthreads();
    unsigned short* Lo = Lb + ((size_t)(Bk + b)) * Nn * Nn;
    for (int k = 0; k < 64; ++k) {
        int idx = tid + k * 256;
        int i = idx >> 7, j = idx & 127;
        float an = apg[idx] * sm.adj.invS[i] + apg[(size_t)j * Nn + i] * sm.adj.invS[j];
        Lo[idx] = f2b(sm.adj.Dv[i] * an * sm.adj.Dv[j]);
    }
}

// ---------------- Chebyshev staging: L A-frags in registers, T1 then T2 ----------------
template <int FIN>
__device__ __forceinline__ void st_cheb(SMem& sm, int tid, int c0blk, int z,
                                        const unsigned short* __restrict__ Lb,
                                        const float* __restrict__ xin,
                                        unsigned short* __restrict__ Xb) {
    constexpr int LDK = 136;
    unsigned short* XsT = sm.cheb.XsT;
    unsigned short* T1T = sm.cheb.T1T;
    int b = z & 31, rel = z >> 5;
    int c0 = c0blk * 32;
    int w = tid >> 6, lane = tid & 63, quad = lane >> 4, lr = lane & 15;
    const unsigned short* Lp = Lb + ((size_t)(rel * Bk + b)) * Nn * Nn;
    const float* Xp = xin + (size_t)b * Nn * FIN;
    const int ld6 = 6 * FIN;
    unsigned short* Xo = Xb + (size_t)b * Nn * ld6 + rel * 3 * FIN;

    short8 aL[2][4];
#pragma unroll
    for (int rt = 0; rt < 2; ++rt) {
        int row = w * 32 + rt * 16 + lr;
#pragma unroll
        for (int kc = 0; kc < 4; ++kc)
            aL[rt][kc] = *(const short8*)(Lp + (size_t)row * Nn + kc * 32 + quad * 8);
    }
    {
        int node = tid >> 1, cb = (tid & 1) * 16;
        const float* xr = Xp + (size_t)node * FIN + c0 + cb;
        unsigned short* t0w = Xo + (size_t)node * ld6 + c0 + cb;
#pragma unroll
        for (int i = 0; i < 4; ++i) {
            float4 vv = *(const float4*)(xr + i * 4);
            ushort4 o;
            o.x = f2b(vv.x); o.y = f2b(vv.y); o.z = f2b(vv.z); o.w = f2b(vv.w);
            *(ushort4*)(t0w + i * 4) = o;
            XsT[(cb + i * 4 + 0) * LDK + node] = o.x;
            XsT[(cb + i * 4 + 1) * LDK + node] = o.y;
            XsT[(cb + i * 4 + 2) * LDK + node] = o.z;
            XsT[(cb + i * 4 + 3) * LDK + node] = o.w;
        }
    }
    __syncthreads();

    floatx4 acc1[2][2];
#pragma unroll
    for (int rt = 0; rt < 2; ++rt)
#pragma unroll
        for (int ct = 0; ct < 2; ++ct) acc1[rt][ct] = (floatx4){0.f, 0.f, 0.f, 0.f};
#pragma unroll
    for (int kc = 0; kc < 4; ++kc) {
        short8 bb[2];
#pragma unroll
        for (int ct = 0; ct < 2; ++ct)
            bb[ct] = *(const short8*)&XsT[(ct * 16 + lr) * LDK + kc * 32 + quad * 8];
#pragma unroll
        for (int rt = 0; rt < 2; ++rt)
#pragma unroll
            for (int ct = 0; ct < 2; ++ct)
                acc1[rt][ct] = __builtin_amdgcn_mfma_f32_16x16x32_bf16(aL[rt][kc], bb[ct], acc1[rt][ct], 0, 0, 0);
    }
#pragma unroll
    for (int rt = 0; rt < 2; ++rt) {
        int rb = (w * 2 + rt) * 16 + quad * 4;
#pragma unroll
        for (int ct = 0; ct < 2; ++ct) {
            int col = ct * 16 + lr;
            ushort4 o;
            o.x = f2b(acc1[rt][ct][0]); o.y = f2b(acc1[rt][ct][1]);
            o.z = f2b(acc1[rt][ct][2]); o.w = f2b(acc1[rt][ct][3]);
            *(ushort4*)&T1T[col * LDK + rb] = o;
        }
    }
    __syncthreads();

    {
        int node = tid >> 1, cb = (tid & 1) * 16;
        unsigned short* t1w = Xo + (size_t)node * ld6 + FIN + c0 + cb;
#pragma unroll
        for (int i = 0; i < 4; ++i) {
            ushort4 o;
            o.x = T1T[(cb + i * 4 + 0) * LDK + node];
            o.y = T1T[(cb + i * 4 + 1) * LDK + node];
            o.z = T1T[(cb + i * 4 + 2) * LDK + node];
            o.w = T1T[(cb + i * 4 + 3) * LDK + node];
            *(ushort4*)(t1w + i * 4) = o;
        }
    }
    floatx4 acc2[2][2];
#pragma unroll
    for (int rt = 0; rt < 2; ++rt)
#pragma unroll
        for (int ct = 0; ct < 2; ++ct) acc2[rt][ct] = (floatx4){0.f, 0.f, 0.f, 0.f};
#pragma unroll
    for (int kc = 0; kc < 4; ++kc) {
        short8 bb[2];
#pragma unroll
        for (int ct = 0; ct < 2; ++ct)
            bb[ct] = *(const short8*)&T1T[(ct * 16 + lr) * LDK + kc * 32 + quad * 8];
#pragma unroll
        for (int rt = 0; rt < 2; ++rt)
#pragma unroll
            for (int ct = 0; ct < 2; ++ct)
                acc2[rt][ct] = __builtin_amdgcn_mfma_f32_16x16x32_bf16(aL[rt][kc], bb[ct], acc2[rt][ct], 0, 0, 0);
    }
#pragma unroll
    for (int rt = 0; rt < 2; ++rt) {
        int rb = (w * 2 + rt) * 16 + quad * 4;
#pragma unroll
        for (int ct = 0; ct < 2; ++ct) {
            int col = ct * 16 + lr;
            ushort4 o;
            float t0a = Xp[(size_t)(rb + 0) * FIN + c0 + col];
            float t0b = Xp[(size_t)(rb + 1) * FIN + c0 + col];
            float t0c = Xp[(size_t)(rb + 2) * FIN + c0 + col];
            float t0d = Xp[(size_t)(rb + 3) * FIN + c0 + col];
            o.x = f2b(2.f * acc2[rt][ct][0] - t0a);
            o.y = f2b(2.f * acc2[rt][ct][1] - t0b);
            o.z = f2b(2.f * acc2[rt][ct][2] - t0c);
            o.w = f2b(2.f * acc2[rt][ct][3] - t0d);
            *(ushort4*)&XsT[col * LDK + rb] = o;
        }
    }
    __syncthreads();
    {
        int node = tid >> 1, cb = (tid & 1) * 16;
        unsigned short* t2w = Xo + (size_t)node * ld6 + 2 * FIN + c0 + cb;
#pragma unroll
        for (int i = 0; i < 4; ++i) {
            ushort4 o;
            o.x = XsT[(cb + i * 4 + 0) * LDK + node];
            o.y = XsT[(cb + i * 4 + 1) * LDK + node];
            o.z = XsT[(cb + i * 4 + 2) * LDK + node];
            o.w = XsT[(cb + i * 4 + 3) * LDK + node];
            *(ushort4*)(t2w + i * 4) = o;
        }
    }
}

// ---------------- fc via bf16 MFMA + fused bias/mask/BN/relu (+pool+classifier) ----------------
template <int RT, bool POOL>
__device__ __forceinline__ void st_fc(SMem& sm, int tid, int bx, int by,
                                      const unsigned short* __restrict__ Xb,
                                      const unsigned short* __restrict__ Wt,
                                      const float* __restrict__ bias,
                                      const float* __restrict__ mask,
                                      const float* __restrict__ bnG,
                                      const float* __restrict__ bnB,
                                      const float* __restrict__ bnM,
                                      const float* __restrict__ bnV,
                                      float* __restrict__ out,
                                      const float* __restrict__ Wc,
                                      const float* __restrict__ bc,
                                      float* __restrict__ outc,
                                      int Kd, int F) {
    unsigned short* As = sm.fc.As;
    unsigned short* Bs = sm.fc.Bs;
    int w = tid >> 6, lane = tid & 63, quad = lane >> 4, lr = lane & 15;
    int row0 = by * (RT * 64), col0 = bx * 64;

    floatx4 acc[RT][4];
#pragma unroll
    for (int rt = 0; rt < RT; ++rt)
#pragma unroll
        for (int ct = 0; ct < 4; ++ct) acc[rt][ct] = (floatx4){0.f, 0.f, 0.f, 0.f};

    int arow[RT], asub[RT];
#pragma unroll
    for (int i = 0; i < RT; ++i) { int ch = tid + i * 256; arow[i] = ch >> 2; asub[i] = ch & 3; }
    int brow = tid >> 2, bsub = tid & 3;

    for (int k0 = 0; k0 < Kd; k0 += 32) {
        short8 ra[RT];
#pragma unroll
        for (int i = 0; i < RT; ++i)
            ra[i] = *(const short8*)(Xb + (size_t)(row0 + arow[i]) * Kd + k0 + asub[i] * 8);
        short8 rb = *(const short8*)(Wt + (size_t)(col0 + brow) * Kd + k0 + bsub * 8);
        __syncthreads();
#pragma unroll
        for (int i = 0; i < RT; ++i)
            *(short8*)&As[arow[i] * 40 + asub[i] * 8] = ra[i];
        *(short8*)&Bs[brow * 40 + bsub * 8] = rb;
        __syncthreads();
        short8 av[RT], bv[4];
#pragma unroll
        for (int rt = 0; rt < RT; ++rt)
            av[rt] = *(const short8*)&As[(w * RT * 16 + rt * 16 + lr) * 40 + quad * 8];
#pragma unroll
        for (int ct = 0; ct < 4; ++ct)
            bv[ct] = *(const short8*)&Bs[(ct * 16 + lr) * 40 + quad * 8];
#pragma unroll
        for (int rt = 0; rt < RT; ++rt)
#pragma unroll
            for (int ct = 0; ct < 4; ++ct)
                acc[rt][ct] = __builtin_amdgcn_mfma_f32_16x16x32_bf16(av[rt], bv[ct], acc[rt][ct], 0, 0, 0);
    }

    float cm[4] = {0.f, 0.f, 0.f, 0.f};
#pragma unroll
    for (int rt = 0; rt < RT; ++rt) {
        int rbase = row0 + w * RT * 16 + rt * 16 + quad * 4;
#pragma unroll
        for (int ct = 0; ct < 4; ++ct) {
            int col = col0 + ct * 16 + lr;
            float bi = bias[col];
            float sc = rsqrtf(bnV[col] + BN_EPS) * bnG[col];
            float bm = bnM[col], bb = bnB[col];
#pragma unroll
            for (int reg = 0; reg < 4; ++reg) {
                int row = rbase + reg;
                float h = acc[rt][ct][reg] + bi;
                h *= mask[row];
                h = (h - bm) * sc + bb;
                h = fmaxf(h, 0.f);
                if (POOL) cm[ct] = fmaxf(cm[ct], h);
                else      out[(size_t)row * F + col] = h;
            }
        }
    }
    if (POOL) {
#pragma unroll
        for (int ct = 0; ct < 4; ++ct) {
            cm[ct] = fmaxf(cm[ct], __shfl_xor(cm[ct], 16));
            cm[ct] = fmaxf(cm[ct], __shfl_xor(cm[ct], 32));
            if (quad == 0) sm.fc.wmax[w][ct * 16 + lr] = cm[ct];
        }
        __syncthreads();
        if (tid < 64) {
            float g = fmaxf(fmaxf(sm.fc.wmax[0][tid], sm.fc.wmax[1][tid]),
                            fmaxf(sm.fc.wmax[2][tid], sm.fc.wmax[3][tid]));
            float s[10];
#pragma unroll
            for (int o = 0; o < 10; ++o) s[o] = g * Wc[(size_t)(col0 + tid) * 10 + o];
#pragma unroll
            for (int ofs = 32; ofs > 0; ofs >>= 1)
#pragma unroll
                for (int o = 0; o < 10; ++o) s[o] += __shfl_down(s[o], ofs);
            if (tid == 0) {
#pragma unroll
                for (int o = 0; o < 10; ++o) {
                    float v = s[o] + ((bx == 0) ? bc[o] : 0.f);
                    atomicAdd(&outc[by * 10 + o], v);
                }
            }
        }
    }
}

// ---------------- the single persistent kernel ----------------
__global__ __launch_bounds__(256, 2) void mega(MArgs a) {
    __shared__ SMem sm;
    int tid = threadIdx.x, bid = blockIdx.x;

    // P0: prep (765) + ap zero (32) = 797 vb
    for (int vb = bid; vb < 797; vb += GRIDN) { st_prep(sm, vb, tid, a); __syncthreads(); }
    gsync();
    // P1: uv (64) + A-path L rel0 (32)
    for (int vb = bid; vb < 96; vb += GRIDN) {
        if (vb < 64) st_uv(sm, tid, vb & 1, vb >> 1, a.xb0, a.Wt + WUV_OFS, a.eb1, a.uv);
        else         st_adjA(sm, tid, vb - 64, a.A, a.Lb);
        __syncthreads();
    }
    gsync();
    // P2: edge scores (1152) + cheb layer0 rel0 (128)
    for (int vb = bid; vb < 1280; vb += GRIDN) {
        if (vb < 1152) st_edge(sm, tid, vb % 36, vb / 36, a.uv, a.eW2, a.eb2, a.mask, a.ap);
        else { int v = vb - 1152; st_cheb<128>(sm, tid, v & 3, v >> 2, a.Lb, a.x, a.Xb); }
        __syncthreads();
    }
    gsync();
    // P3: An-path L rel1 (32)
    for (int vb = bid; vb < 32; vb += GRIDN) { st_adjAn(sm, tid, vb, a.ap, a.Lb); __syncthreads(); }
    gsync();
    // P4: cheb layer0 rel1 (128)
    for (int vb = bid; vb < 128; vb += GRIDN) { st_cheb<128>(sm, tid, vb & 3, 32 + (vb >> 2), a.Lb, a.x, a.Xb); __syncthreads(); }
    gsync();
    // P5: fc0 (64)
    for (int vb = bid; vb < 64; vb += GRIDN) {
        st_fc<1, false>(sm, tid, 0, vb, a.Xb, a.Wt, a.gb0, a.mask, a.gg0, a.gB0, a.gm0, a.gv0,
                        a.h0, nullptr, nullptr, nullptr, 768, 64);
        __syncthreads();
    }
    gsync();
    // P6: cheb layer1 both rels (128)
    for (int vb = bid; vb < 128; vb += GRIDN) { st_cheb<64>(sm, tid, vb & 1, vb >> 1, a.Lb, a.h0, a.Xb); __syncthreads(); }
    gsync();
    // P7: fc1 (128)
    for (int vb = bid; vb < 128; vb += GRIDN) {
        st_fc<2, false>(sm, tid, vb & 3, vb >> 2, a.Xb, a.Wt + 49152, a.gb1, a.mask, a.gg1, a.gB1, a.gm1, a.gv1,
                        a.h1, nullptr, nullptr, nullptr, 384, 256);
        __syncthreads();
    }
    gsync();
    // P8: cheb layer2 both rels (512)
    for (int vb = bid; vb < 512; vb += GRIDN) { st_cheb<256>(sm, tid, vb & 7, vb >> 3, a.Lb, a.h1, a.Xb); __syncthreads(); }
    gsync();
    // P9: fc2 + pool + folded classifier (256)
    for (int vb = bid; vb < 256; vb += GRIDN) {
        st_fc<2, true>(sm, tid, vb & 7, vb >> 3, a.Xb, a.Wt + 147456, a.gb2, a.mask, a.gg2, a.gB2, a.gm2, a.gv2,
                       nullptr, a.Wc, a.bc, a.outc, 1536, 512);
        __syncthreads();
    }
}

extern "C" void kernel_launch(void* const* d_in, const int* in_sizes, int n_in,
                              void* d_out, int out_size, void* d_ws, size_t ws_size,
                              hipStream_t stream) {
    (void)in_sizes; (void)n_in; (void)ws_size;
    float* ws = (float*)d_ws;

    MArgs a;
    a.x    = (const float*)d_in[0];
    a.A    = (const float*)d_in[1];
    a.mask = (const float*)d_in[2];
    a.eW1  = (const float*)d_in[3];
    a.eb1  = (const float*)d_in[4];
    a.eW2  = (const float*)d_in[5];
    a.eb2  = (const float*)d_in[6];
    a.W0   = (const float*)d_in[7];
    a.gb0  = (const float*)d_in[8];  a.gg0 = (const float*)d_in[9];  a.gB0 = (const float*)d_in[10];
    a.gm0  = (const float*)d_in[11]; a.gv0 = (const float*)d_in[12];
    a.W1   = (const float*)d_in[13];
    a.gb1  = (const float*)d_in[14]; a.gg1 = (const float*)d_in[15]; a.gB1 = (const float*)d_in[16];
    a.gm1  = (const float*)d_in[17]; a.gv1 = (const float*)d_in[18];
    a.W2   = (const float*)d_in[19];
    a.gb2  = (const float*)d_in[20]; a.gg2 = (const float*)d_in[21]; a.gB2 = (const float*)d_in[22];
    a.gm2  = (const float*)d_in[23]; a.gv2 = (const float*)d_in[24];
    a.fW1  = (const float*)d_in[25]; a.fb1 = (const float*)d_in[26];
    a.fW2  = (const float*)d_in[27]; a.fb2 = (const float*)d_in[28];

    a.uv  = ws + OFF_UV;
    a.ap  = ws + OFF_AP;
    a.h0  = ws + OFF_H0;
    a.h1  = ws + OFF_H1;
    a.Wc  = ws + OFF_WC;
    a.bc  = ws + OFF_BC;
    a.Lb  = (unsigned short*)(ws + OFF_LB);
    a.xb0 = (unsigned short*)(ws + OFF_XB0);
    a.Xb  = (unsigned short*)(ws + OFF_XB);
    a.Wt  = (unsigned short*)(ws + OFF_WT);
    a.outc = (float*)d_out;

    hipMemsetAsync(d_out, 0, (size_t)out_size * sizeof(float), stream);
    mega<<<GRIDN, 256, 0, stream>>>(a);
}

// Round 4
// 394.028 us; speedup vs baseline: 2.0148x; 2.0148x over previous
//
#include <hip/hip_runtime.h>

// ---------------- constants ----------------
#define Bk 32      // batch
#define Nn 128     // nodes
#define Cc 128     // in channels
#define BN_EPS 1e-5f
#define GRIDN 512  // persistent grid: 2 blocks/CU on 256 CUs (co-residency guaranteed
                   // by __launch_bounds__(256,2): VGPR<=256, LDS union 27.6KB)

typedef __attribute__((ext_vector_type(8))) short short8;
typedef __attribute__((ext_vector_type(4))) float floatx4;

// workspace offsets (floats) -- per-layer Xb regions are now DISJOINT because
// batches run pipelined (batch 3 may write layer-1 while batch 5 reads layer-0).
#define OFF_UV   ((size_t)0)         // 524288  uv f32 [4096][128]
#define OFF_AP   ((size_t)524288)    // 524288  masked exp scores (ONLY strict upper-tri written)
#define OFF_LB   ((size_t)1048576)   // 524288 f = bf16 L [2 rel][32 b][128][128]
#define OFF_H0   ((size_t)1572864)   // 262144
#define OFF_H1   ((size_t)1835008)   // 1048576 -> ends 2883584
#define OFF_WC   ((size_t)2883584)   // 5120
#define OFF_BC   ((size_t)2888704)   // 16 -> 2888720
#define OFF_XL0  ((size_t)2888720)   // 1572864 f = bf16 Xcat L0 [4096][768]
#define OFF_XL1  ((size_t)4461584)   // 786432 f  = bf16 Xcat L1 [4096][384]
#define OFF_XL2  ((size_t)5248016)   // 3145728 f = bf16 Xcat L2 [4096][1536]
#define OFF_WT   ((size_t)8393744)   // 466944 f (Wt0,Wt1,Wt2)
#define OFF_FL   ((size_t)8868880)   // 3584 uints: per-batch flag counters

__device__ __forceinline__ unsigned short f2b(float f) {
    unsigned int x = __float_as_uint(f);
    unsigned int r = x + 0x7FFFu + ((x >> 16) & 1u);
    return (unsigned short)(r >> 16);
}

// ---------------- LDS union: max member = uv (27.6 KB) ----------------
union __align__(16) SMem {
    struct { unsigned short Ts[64][65]; } prep;                                  //  8.3 KB
    struct { unsigned short As[128 * 40]; unsigned short Bs[64 * 136]; } uv;     // 27.6 KB
    struct { float ui[16][68]; float vi[16][68];
             float uj[16][68]; float vj[16][68]; float w2[64]; } edge;           // 17.7 KB
    struct { float part[256]; float invS[128]; float t1S[128]; float Dv[128]; } adj; // 2.5 KB
    struct { unsigned short XsT[32 * 136]; unsigned short T1T[32 * 136]; } cheb; // 17.4 KB
    struct { unsigned short As[2 * 64 * 40]; unsigned short Bs[64 * 40];
             float wmax[4][64]; } fc;                                            // 16.4 KB
};

// ---------------- ONE global barrier: contention-free slot barrier ----------------
// Each block stores a generation number into its own padded slot (no RMW contention);
// block 0's 256 threads scan all 512 slots in parallel, then bump g_gen2.
__device__ unsigned g_slot[GRIDN * 4];   // 16B-padded slots
__device__ unsigned g_gen2 = 0;

__device__ __forceinline__ void gsync(int bid) {
    __syncthreads();
    int tid = threadIdx.x;
    unsigned tgt = 0;
    if (tid == 0) {
        __threadfence();   // release this block's phase writes
        tgt = __hip_atomic_load(&g_gen2, __ATOMIC_RELAXED, __HIP_MEMORY_SCOPE_AGENT) + 1u;
        __hip_atomic_store(&g_slot[bid * 4], tgt, __ATOMIC_RELAXED, __HIP_MEMORY_SCOPE_AGENT);
    }
    if (bid == 0) {
        unsigned tg = __hip_atomic_load(&g_gen2, __ATOMIC_RELAXED, __HIP_MEMORY_SCOPE_AGENT) + 1u;
        for (;;) {
            unsigned v0 = __hip_atomic_load(&g_slot[(2 * tid) * 4], __ATOMIC_RELAXED, __HIP_MEMORY_SCOPE_AGENT);
            unsigned v1 = __hip_atomic_load(&g_slot[(2 * tid + 1) * 4], __ATOMIC_RELAXED, __HIP_MEMORY_SCOPE_AGENT);
            if (__syncthreads_and((int)(v0 >= tg && v1 >= tg))) break;
            __builtin_amdgcn_s_sleep(2);
        }
        if (tid == 0) {
            __threadfence();   // relay: acquire slot writers + release for gen readers
            __hip_atomic_fetch_add(&g_gen2, 1u, __ATOMIC_RELAXED, __HIP_MEMORY_SCOPE_AGENT);
        }
    }
    if (tid == 0) {
        while (__hip_atomic_load(&g_gen2, __ATOMIC_RELAXED, __HIP_MEMORY_SCOPE_AGENT) < tgt)
            __builtin_amdgcn_s_sleep(2);
        __threadfence();   // acquire
    }
    __syncthreads();
}

// ---------------- per-batch dataflow flags (<=16 arrivals each, private lines) ----------------
enum { AEDGE = 0, AL1 = 1, AL0 = 2, AH0 = 3, AX1 = 4, AH1 = 5, AX2 = 6 };
#define FID(arr, b) ((((arr) * 32) + (b)) * 16)
#define NFLAGU 3584   // 7 arrays * 32 batches * 16-uint padding

__device__ __forceinline__ void fl_arrive(unsigned* f) {
    __syncthreads();   // all block threads' writes issued
    if (threadIdx.x == 0) {
        __threadfence();   // release
        __hip_atomic_fetch_add(f, 1u, __ATOMIC_RELAXED, __HIP_MEMORY_SCOPE_AGENT);
    }
}
__device__ __forceinline__ void fl_wait(const unsigned* f, unsigned tgt) {
    if (threadIdx.x == 0) {
        while (__hip_atomic_load(f, __ATOMIC_RELAXED, __HIP_MEMORY_SCOPE_AGENT) < tgt)
            __builtin_amdgcn_s_sleep(2);
        __threadfence();   // acquire
    }
    __syncthreads();
}

// ---------------- args ----------------
struct MArgs {
    const float *x, *A, *mask, *eW1, *eb1, *eW2, *eb2;
    const float *W0, *W1, *W2;
    const float *gb0, *gg0, *gB0, *gm0, *gv0;
    const float *gb1, *gg1, *gB1, *gm1, *gv1;
    const float *gb2, *gg2, *gB2, *gm2, *gv2;
    const float *fW1, *fb1, *fW2, *fb2;
    float *uv, *ap, *h0, *h1, *Wc, *bc;
    unsigned short *Lb, *XbL0, *XbL1, *XbL2, *Wt;
    unsigned *flags;
    float *outc;
};

// ---------------- P0 units: weight transposes, folded classifier, flag zero ----------------
__device__ __forceinline__ void st_prep(SMem& sm, int vb, int tid, const MArgs& a) {
    if (vb < 228) {
        const float* src; unsigned short* dst; int N, ldK, k0, n0;
        if (vb < 12)      { src = a.W0; dst = a.Wt;          N = 64;  ldK = 768;  k0 = vb * 64;       n0 = 0; }
        else if (vb < 36) { int t = vb - 12; src = a.W1; dst = a.Wt + 49152;  N = 256; ldK = 384;  k0 = (t % 6) * 64;  n0 = (t / 6) * 64; }
        else              { int t = vb - 36; src = a.W2; dst = a.Wt + 147456; N = 512; ldK = 1536; k0 = (t % 24) * 64; n0 = (t / 24) * 64; }
#pragma unroll
        for (int p = 0; p < 16; ++p) {
            int e = tid + p * 256; int r = e >> 6, c = e & 63;
            sm.prep.Ts[r][c] = f2b(src[(size_t)(k0 + r) * N + n0 + c]);
        }
        __syncthreads();
#pragma unroll
        for (int p = 0; p < 16; ++p) {
            int e = tid + p * 256; int n = e >> 6, k = e & 63;
            dst[(size_t)(n0 + n) * ldK + k0 + k] = sm.prep.Ts[k][n];
        }
    } else if (vb < 249) {
        int e = (vb - 228) * 256 + tid;
        if (e < 5120) {
            int i = e / 10, j = e - i * 10;
            float acc = 0.f;
            for (int h = 0; h < 256; ++h) acc += a.fW1[(size_t)i * 256 + h] * a.fW2[(size_t)h * 10 + j];
            a.Wc[e] = acc;
        } else if (e < 5130) {
            int j = e - 5120;
            float acc = a.fb2[j];
            for (int h = 0; h < 256; ++h) acc += a.fb1[h] * a.fW2[(size_t)h * 10 + j];
            a.bc[j] = acc;
        }
    } else { // vb == 249: zero the per-batch flag counters (fresh each launch; ws is re-poisoned)
        for (int i = tid; i < NFLAGU; i += 256) a.flags[i] = 0u;
    }
}

// ---------------- P0 unit: uv = x @ Wuv (+eb1 on u cols); self-contained (f32 x, eW1 in LDS) ----------------
__device__ __forceinline__ void st_uv(SMem& sm, int tid, int bx, int by,
                                      const float* __restrict__ x,
                                      const float* __restrict__ eW1,
                                      const float* __restrict__ eb1,
                                      float* __restrict__ uv) {
    unsigned short* As = sm.uv.As;
    unsigned short* Bs = sm.uv.Bs;
    int w = tid >> 6, lane = tid & 63, quad = lane >> 4, lr = lane & 15;
    int row0 = by * 128, col0 = bx * 64;
    // stage Wuv^T tile: Bs[c][k] = bf16(eW1[(bx*128+k)*64 + c]); coalesced over c
    {
        int c = tid & 63, kk = tid >> 6;
#pragma unroll
        for (int p = 0; p < 32; ++p) {
            int k = kk * 32 + p;
            Bs[c * 136 + k] = f2b(eW1[(size_t)(bx * 128 + k) * 64 + c]);
        }
    }
    floatx4 acc[2][4];
#pragma unroll
    for (int rt = 0; rt < 2; ++rt)
#pragma unroll
        for (int ct = 0; ct < 4; ++ct) acc[rt][ct] = (floatx4){0.f, 0.f, 0.f, 0.f};
    int arow[2], asub[2];
#pragma unroll
    for (int i = 0; i < 2; ++i) { int ch = tid + i * 256; arow[i] = ch >> 2; asub[i] = ch & 3; }
    for (int k0 = 0; k0 < 128; k0 += 32) {
        short8 ra[2];
#pragma unroll
        for (int i = 0; i < 2; ++i) {
            const float* xp = x + (size_t)(row0 + arow[i]) * 128 + k0 + asub[i] * 8;
            float4 f0 = *(const float4*)xp;
            float4 f1 = *(const float4*)(xp + 4);
            ra[i][0] = (short)f2b(f0.x); ra[i][1] = (short)f2b(f0.y);
            ra[i][2] = (short)f2b(f0.z); ra[i][3] = (short)f2b(f0.w);
            ra[i][4] = (short)f2b(f1.x); ra[i][5] = (short)f2b(f1.y);
            ra[i][6] = (short)f2b(f1.z); ra[i][7] = (short)f2b(f1.w);
        }
        __syncthreads();
#pragma unroll
        for (int i = 0; i < 2; ++i) *(short8*)&As[arow[i] * 40 + asub[i] * 8] = ra[i];
        __syncthreads();
        short8 av[2], bv[4];
#pragma unroll
        for (int rt = 0; rt < 2; ++rt)
            av[rt] = *(const short8*)&As[(w * 32 + rt * 16 + lr) * 40 + quad * 8];
#pragma unroll
        for (int ct = 0; ct < 4; ++ct)
            bv[ct] = *(const short8*)&Bs[(ct * 16 + lr) * 136 + k0 + quad * 8];
#pragma unroll
        for (int rt = 0; rt < 2; ++rt)
#pragma unroll
            for (int ct = 0; ct < 4; ++ct)
                acc[rt][ct] = __builtin_amdgcn_mfma_f32_16x16x32_bf16(av[rt], bv[ct], acc[rt][ct], 0, 0, 0);
    }
#pragma unroll
    for (int rt = 0; rt < 2; ++rt) {
        int rbase = row0 + w * 32 + rt * 16 + quad * 4;
#pragma unroll
        for (int ct = 0; ct < 4; ++ct) {
            int col = col0 + ct * 16 + lr;
            float bi = (col < 64) ? eb1[col] : 0.f;
#pragma unroll
            for (int reg = 0; reg < 4; ++reg)
                uv[(size_t)(rbase + reg) * 128 + col] = acc[rt][ct][reg] + bi;
        }
    }
}

// ---------------- P0 unit: A-path Laplacian (rel0) ----------------
__device__ __forceinline__ void st_adjA(SMem& sm, int tid, int b,
                                        const float* __restrict__ A,
                                        unsigned short* __restrict__ Lb) {
    const float* Ar = A + (size_t)b * Nn * Nn;
    int j = tid & 127, half = tid >> 7;
    float sum = 0.f;
    for (int i = half * 64; i < half * 64 + 64; ++i) sum += Ar[i * Nn + j];
    sm.adj.part[tid] = sum;
    __syncthreads();
    if (tid < 128) sm.adj.Dv[tid] = rsqrtf(sm.adj.part[tid] + sm.adj.part[tid + 128] + 1e-5f);
    __syncthreads();
    unsigned short* Lo = Lb + (size_t)b * Nn * Nn;
    for (int k = 0; k < 64; ++k) {
        int idx = tid + k * 256;
        int i = idx >> 7, jj = idx & 127;
        Lo[idx] = f2b(sm.adj.Dv[i] * Ar[idx] * sm.adj.Dv[jj]);
    }
}

// ---------------- edge scores (upper-tri tile pairs; writes ONLY gj>gi) ----------------
__device__ __forceinline__ void st_edge(SMem& sm, int tid, int t, int b,
                                        const float* __restrict__ uv,
                                        const float* __restrict__ eW2,
                                        const float* __restrict__ eb2,
                                        const float* __restrict__ mask,
                                        float* __restrict__ ap) {
    int ti = 0, rem = t;
    for (;;) { int w = 8 - ti; if (rem < w) break; rem -= w; ++ti; }
    int tj = ti + rem;
    int i0 = ti * 16, j0 = tj * 16;
    int r = tid >> 4, c4 = (tid & 15) * 4;
    const float* uvb = uv + (size_t)b * Nn * 128;
    *(float4*)&sm.edge.ui[r][c4] = *(const float4*)(uvb + (size_t)(i0 + r) * 128 + c4);
    *(float4*)&sm.edge.vi[r][c4] = *(const float4*)(uvb + (size_t)(i0 + r) * 128 + 64 + c4);
    *(float4*)&sm.edge.uj[r][c4] = *(const float4*)(uvb + (size_t)(j0 + r) * 128 + c4);
    *(float4*)&sm.edge.vj[r][c4] = *(const float4*)(uvb + (size_t)(j0 + r) * 128 + 64 + c4);
    if (tid < 64) sm.edge.w2[tid] = eW2[tid];
    __syncthreads();
    int il = tid >> 4, jl = tid & 15;
    int gi = i0 + il, gj = j0 + jl;
    if (gj > gi) {
        float d = 0.f;
#pragma unroll
        for (int h4 = 0; h4 < 16; ++h4) {
            float4 a1 = *(const float4*)&sm.edge.ui[il][h4 * 4];
            float4 b1 = *(const float4*)&sm.edge.vj[jl][h4 * 4];
            float4 a2 = *(const float4*)&sm.edge.uj[jl][h4 * 4];
            float4 b2 = *(const float4*)&sm.edge.vi[il][h4 * 4];
            float4 ww = *(const float4*)&sm.edge.w2[h4 * 4];
            d += (fmaxf(a1.x + b1.x, 0.f) + fmaxf(a2.x + b2.x, 0.f)) * ww.x
               + (fmaxf(a1.y + b1.y, 0.f) + fmaxf(a2.y + b2.y, 0.f)) * ww.y
               + (fmaxf(a1.z + b1.z, 0.f) + fmaxf(a2.z + b2.z, 0.f)) * ww.z
               + (fmaxf(a1.w + b1.w, 0.f) + fmaxf(a2.w + b2.w, 0.f)) * ww.w;
        }
        float p = 0.5f * d + eb2[0];
        float mi = mask[b * Nn + gi], mj = mask[b * Nn + gj];
        float val = (mi != 0.f && mj != 0.f) ? expf(fminf(p, 80.f)) : 0.f;
        ap[((size_t)(b * Nn + gi)) * Nn + gj] = val;
    }
}

// ---------------- An-path Laplacian (rel1): reads ONLY upper-tri of ap (guards) ----------------
__device__ __forceinline__ void st_adjAn(SMem& sm, int tid, int b,
                                         const float* __restrict__ ap,
                                         unsigned short* __restrict__ Lb) {
    const float* apg = ap + (size_t)b * Nn * Nn;
    {   // row sums over j>i only (lower/diag never written)
        int row = tid >> 1, half = tid & 1;
        float s0 = 0.f;
        for (int jj = half * 64; jj < half * 64 + 64; ++jj)
            if (jj > row) s0 += apg[(size_t)row * Nn + jj];
        sm.adj.part[tid] = s0;
    }
    __syncthreads();
    if (tid < 128) {
        float rsum = sm.adj.part[tid * 2] + sm.adj.part[tid * 2 + 1];
        sm.adj.invS[tid] = (rsum == 0.f) ? 1.f : (1.f / rsum);
        sm.adj.t1S[tid]  = (rsum == 0.f) ? 0.f : 1.f;
    }
    __syncthreads();
    {   // column sums of ap*invS over i<col only
        int col = tid >> 1, half = tid & 1;
        float s0 = 0.f;
        for (int ii = half * 64; ii < half * 64 + 64; ++ii)
            if (ii < col) s0 += apg[(size_t)ii * Nn + col] * sm.adj.invS[ii];
        sm.adj.part[tid] = s0;
    }
    __syncthreads();
    if (tid < 128)
        sm.adj.Dv[tid] = rsqrtf(sm.adj.t1S[tid] + sm.adj.part[tid * 2] + sm.adj.part[tid * 2 + 1] + 1e-5f);
    __syncthreads();
    unsigned short* Lo = Lb + ((size_t)(Bk + b)) * Nn * Nn;
    for (int k = 0; k < 64; ++k) {
        int idx = tid + k * 256;
        int i = idx >> 7, j = idx & 127;
        float an = 0.f;
        if (i != j) {
            int p = i < j ? i : j, q = i < j ? j : i;
            an = apg[(size_t)p * Nn + q] * sm.adj.invS[p];
        }
        Lo[idx] = f2b(sm.adj.Dv[i] * an * sm.adj.Dv[j]);
    }
}

// ---------------- Chebyshev staging: L A-frags in registers, T1 then T2 ----------------
template <int FIN>
__device__ __forceinline__ void st_cheb(SMem& sm, int tid, int c0blk, int z,
                                        const unsigned short* __restrict__ Lb,
                                        const float* __restrict__ xin,
                                        unsigned short* __restrict__ Xb) {
    constexpr int LDK = 136;
    unsigned short* XsT = sm.cheb.XsT;
    unsigned short* T1T = sm.cheb.T1T;
    int b = z & 31, rel = z >> 5;
    int c0 = c0blk * 32;
    int w = tid >> 6, lane = tid & 63, quad = lane >> 4, lr = lane & 15;
    const unsigned short* Lp = Lb + ((size_t)(rel * Bk + b)) * Nn * Nn;
    const float* Xp = xin + (size_t)b * Nn * FIN;
    const int ld6 = 6 * FIN;
    unsigned short* Xo = Xb + (size_t)b * Nn * ld6 + rel * 3 * FIN;

    short8 aL[2][4];
#pragma unroll
    for (int rt = 0; rt < 2; ++rt) {
        int row = w * 32 + rt * 16 + lr;
#pragma unroll
        for (int kc = 0; kc < 4; ++kc)
            aL[rt][kc] = *(const short8*)(Lp + (size_t)row * Nn + kc * 32 + quad * 8);
    }
    {
        int node = tid >> 1, cb = (tid & 1) * 16;
        const float* xr = Xp + (size_t)node * FIN + c0 + cb;
        unsigned short* t0w = Xo + (size_t)node * ld6 + c0 + cb;
#pragma unroll
        for (int i = 0; i < 4; ++i) {
            float4 vv = *(const float4*)(xr + i * 4);
            ushort4 o;
            o.x = f2b(vv.x); o.y = f2b(vv.y); o.z = f2b(vv.z); o.w = f2b(vv.w);
            *(ushort4*)(t0w + i * 4) = o;
            XsT[(cb + i * 4 + 0) * LDK + node] = o.x;
            XsT[(cb + i * 4 + 1) * LDK + node] = o.y;
            XsT[(cb + i * 4 + 2) * LDK + node] = o.z;
            XsT[(cb + i * 4 + 3) * LDK + node] = o.w;
        }
    }
    __syncthreads();

    floatx4 acc1[2][2];
#pragma unroll
    for (int rt = 0; rt < 2; ++rt)
#pragma unroll
        for (int ct = 0; ct < 2; ++ct) acc1[rt][ct] = (floatx4){0.f, 0.f, 0.f, 0.f};
#pragma unroll
    for (int kc = 0; kc < 4; ++kc) {
        short8 bb[2];
#pragma unroll
        for (int ct = 0; ct < 2; ++ct)
            bb[ct] = *(const short8*)&XsT[(ct * 16 + lr) * LDK + kc * 32 + quad * 8];
#pragma unroll
        for (int rt = 0; rt < 2; ++rt)
#pragma unroll
            for (int ct = 0; ct < 2; ++ct)
                acc1[rt][ct] = __builtin_amdgcn_mfma_f32_16x16x32_bf16(aL[rt][kc], bb[ct], acc1[rt][ct], 0, 0, 0);
    }
#pragma unroll
    for (int rt = 0; rt < 2; ++rt) {
        int rb = (w * 2 + rt) * 16 + quad * 4;
#pragma unroll
        for (int ct = 0; ct < 2; ++ct) {
            int col = ct * 16 + lr;
            ushort4 o;
            o.x = f2b(acc1[rt][ct][0]); o.y = f2b(acc1[rt][ct][1]);
            o.z = f2b(acc1[rt][ct][2]); o.w = f2b(acc1[rt][ct][3]);
            *(ushort4*)&T1T[col * LDK + rb] = o;
        }
    }
    __syncthreads();

    {
        int node = tid >> 1, cb = (tid & 1) * 16;
        unsigned short* t1w = Xo + (size_t)node * ld6 + FIN + c0 + cb;
#pragma unroll
        for (int i = 0; i < 4; ++i) {
            ushort4 o;
            o.x = T1T[(cb + i * 4 + 0) * LDK + node];
            o.y = T1T[(cb + i * 4 + 1) * LDK + node];
            o.z = T1T[(cb + i * 4 + 2) * LDK + node];
            o.w = T1T[(cb + i * 4 + 3) * LDK + node];
            *(ushort4*)(t1w + i * 4) = o;
        }
    }
    floatx4 acc2[2][2];
#pragma unroll
    for (int rt = 0; rt < 2; ++rt)
#pragma unroll
        for (int ct = 0; ct < 2; ++ct) acc2[rt][ct] = (floatx4){0.f, 0.f, 0.f, 0.f};
#pragma unroll
    for (int kc = 0; kc < 4; ++kc) {
        short8 bb[2];
#pragma unroll
        for (int ct = 0; ct < 2; ++ct)
            bb[ct] = *(const short8*)&T1T[(ct * 16 + lr) * LDK + kc * 32 + quad * 8];
#pragma unroll
        for (int rt = 0; rt < 2; ++rt)
#pragma unroll
            for (int ct = 0; ct < 2; ++ct)
                acc2[rt][ct] = __builtin_amdgcn_mfma_f32_16x16x32_bf16(aL[rt][kc], bb[ct], acc2[rt][ct], 0, 0, 0);
    }
#pragma unroll
    for (int rt = 0; rt < 2; ++rt) {
        int rb = (w * 2 + rt) * 16 + quad * 4;
#pragma unroll
        for (int ct = 0; ct < 2; ++ct) {
            int col = ct * 16 + lr;
            ushort4 o;
            float t0a = Xp[(size_t)(rb + 0) * FIN + c0 + col];
            float t0b = Xp[(size_t)(rb + 1) * FIN + c0 + col];
            float t0c = Xp[(size_t)(rb + 2) * FIN + c0 + col];
            float t0d = Xp[(size_t)(rb + 3) * FIN + c0 + col];
            o.x = f2b(2.f * acc2[rt][ct][0] - t0a);
            o.y = f2b(2.f * acc2[rt][ct][1] - t0b);
            o.z = f2b(2.f * acc2[rt][ct][2] - t0c);
            o.w = f2b(2.f * acc2[rt][ct][3] - t0d);
            *(ushort4*)&XsT[col * LDK + rb] = o;
        }
    }
    __syncthreads();
    {
        int node = tid >> 1, cb = (tid & 1) * 16;
        unsigned short* t2w = Xo + (size_t)node * ld6 + 2 * FIN + c0 + cb;
#pragma unroll
        for (int i = 0; i < 4; ++i) {
            ushort4 o;
            o.x = XsT[(cb + i * 4 + 0) * LDK + node];
            o.y = XsT[(cb + i * 4 + 1) * LDK + node];
            o.z = XsT[(cb + i * 4 + 2) * LDK + node];
            o.w = XsT[(cb + i * 4 + 3) * LDK + node];
            *(ushort4*)(t2w + i * 4) = o;
        }
    }
}

// ---------------- fc via bf16 MFMA + fused bias/mask/BN/relu (+pool+classifier) ----------------
template <int RT, bool POOL>
__device__ __forceinline__ void st_fc(SMem& sm, int tid, int bx, int by,
                                      const unsigned short* __restrict__ Xb,
                                      const unsigned short* __restrict__ Wt,
                                      const float* __restrict__ bias,
                                      const float* __restrict__ mask,
                                      const float* __restrict__ bnG,
                                      const float* __restrict__ bnB,
                                      const float* __restrict__ bnM,
                                      const float* __restrict__ bnV,
                                      float* __restrict__ out,
                                      const float* __restrict__ Wc,
                                      const float* __restrict__ bc,
                                      float* __restrict__ outc,
                                      int Kd, int F) {
    unsigned short* As = sm.fc.As;
    unsigned short* Bs = sm.fc.Bs;
    int w = tid >> 6, lane = tid & 63, quad = lane >> 4, lr = lane & 15;
    int row0 = by * (RT * 64), col0 = bx * 64;

    floatx4 acc[RT][4];
#pragma unroll
    for (int rt = 0; rt < RT; ++rt)
#pragma unroll
        for (int ct = 0; ct < 4; ++ct) acc[rt][ct] = (floatx4){0.f, 0.f, 0.f, 0.f};

    int arow[RT], asub[RT];
#pragma unroll
    for (int i = 0; i < RT; ++i) { int ch = tid + i * 256; arow[i] = ch >> 2; asub[i] = ch & 3; }
    int brow = tid >> 2, bsub = tid & 3;

    for (int k0 = 0; k0 < Kd; k0 += 32) {
        short8 ra[RT];
#pragma unroll
        for (int i = 0; i < RT; ++i)
            ra[i] = *(const short8*)(Xb + (size_t)(row0 + arow[i]) * Kd + k0 + asub[i] * 8);
        short8 rb = *(const short8*)(Wt + (size_t)(col0 + brow) * Kd + k0 + bsub * 8);
        __syncthreads();
#pragma unroll
        for (int i = 0; i < RT; ++i)
            *(short8*)&As[arow[i] * 40 + asub[i] * 8] = ra[i];
        *(short8*)&Bs[brow * 40 + bsub * 8] = rb;
        __syncthreads();
        short8 av[RT], bv[4];
#pragma unroll
        for (int rt = 0; rt < RT; ++rt)
            av[rt] = *(const short8*)&As[(w * RT * 16 + rt * 16 + lr) * 40 + quad * 8];
#pragma unroll
        for (int ct = 0; ct < 4; ++ct)
            bv[ct] = *(const short8*)&Bs[(ct * 16 + lr) * 40 + quad * 8];
#pragma unroll
        for (int rt = 0; rt < RT; ++rt)
#pragma unroll
            for (int ct = 0; ct < 4; ++ct)
                acc[rt][ct] = __builtin_amdgcn_mfma_f32_16x16x32_bf16(av[rt], bv[ct], acc[rt][ct], 0, 0, 0);
    }

    float cm[4] = {0.f, 0.f, 0.f, 0.f};
#pragma unroll
    for (int rt = 0; rt < RT; ++rt) {
        int rbase = row0 + w * RT * 16 + rt * 16 + quad * 4;
#pragma unroll
        for (int ct = 0; ct < 4; ++ct) {
            int col = col0 + ct * 16 + lr;
            float bi = bias[col];
            float sc = rsqrtf(bnV[col] + BN_EPS) * bnG[col];
            float bm = bnM[col], bb = bnB[col];
#pragma unroll
            for (int reg = 0; reg < 4; ++reg) {
                int row = rbase + reg;
                float h = acc[rt][ct][reg] + bi;
                h *= mask[row];
                h = (h - bm) * sc + bb;
                h = fmaxf(h, 0.f);
                if (POOL) cm[ct] = fmaxf(cm[ct], h);
                else      out[(size_t)row * F + col] = h;
            }
        }
    }
    if (POOL) {
#pragma unroll
        for (int ct = 0; ct < 4; ++ct) {
            cm[ct] = fmaxf(cm[ct], __shfl_xor(cm[ct], 16));
            cm[ct] = fmaxf(cm[ct], __shfl_xor(cm[ct], 32));
            if (quad == 0) sm.fc.wmax[w][ct * 16 + lr] = cm[ct];
        }
        __syncthreads();
        if (tid < 64) {
            float g = fmaxf(fmaxf(sm.fc.wmax[0][tid], sm.fc.wmax[1][tid]),
                            fmaxf(sm.fc.wmax[2][tid], sm.fc.wmax[3][tid]));
            float s[10];
#pragma unroll
            for (int o = 0; o < 10; ++o) s[o] = g * Wc[(size_t)(col0 + tid) * 10 + o];
#pragma unroll
            for (int ofs = 32; ofs > 0; ofs >>= 1)
#pragma unroll
                for (int o = 0; o < 10; ++o) s[o] += __shfl_down(s[o], ofs);
            if (tid == 0) {
#pragma unroll
                for (int o = 0; o < 10; ++o) {
                    float v = s[o] + ((bx == 0) ? bc[o] : 0.f);
                    atomicAdd(&outc[by * 10 + o], v);
                }
            }
        }
    }
}

// ---------------- the single persistent kernel: 1 global barrier + per-batch dataflow ----------------
__global__ __launch_bounds__(256, 2) void mega(MArgs a) {
    __shared__ SMem sm;
    int tid = threadIdx.x, bid = blockIdx.x;
    unsigned* FL = a.flags;

    // ---- P0: prep (228 Wt + 21 Wc + 1 flag-zero) + uv (64) + adjA (32) = 346 units, 1 per block ----
    if (bid < 250)      st_prep(sm, bid, tid, a);
    else if (bid < 314) { int v = bid - 250; st_uv(sm, tid, v & 1, v >> 1, a.x, a.eW1, a.eb1, a.uv); }
    else if (bid < 346) st_adjA(sm, tid, bid - 314, a.A, a.Lb);
    gsync(bid);   // the ONLY global barrier

    // ---- per-batch pipeline: 16 blocks per batch, flag-ordered dataflow ----
    int b = bid >> 4, li = bid & 15;

    // edge scores: 36 tiles over 16 blocks (li<4 do 3, rest 2)
    for (int r = 0; r < 3; ++r) {
        int t = li + r * 16;
        if (t < 36) st_edge(sm, tid, t, b, a.uv, a.eW2, a.eb2, a.mask, a.ap);
        __syncthreads();
    }
    fl_arrive(&FL[FID(AEDGE, b)]);

    // leader: An-path Laplacian once all edge tiles of this batch landed
    if (li == 0) {
        fl_wait(&FL[FID(AEDGE, b)], 16);
        st_adjAn(sm, tid, b, a.ap, a.Lb);
        fl_arrive(&FL[FID(AL1, b)]);
    }

    // cheb layer0: rel0 needs nothing new; rel1 waits for Lb rel1
    if (li >= 8 && li < 12) {
        st_cheb<128>(sm, tid, li - 8, b, a.Lb, a.x, a.XbL0);
        fl_arrive(&FL[FID(AL0, b)]);
    }
    if (li >= 4 && li < 8) {
        fl_wait(&FL[FID(AL1, b)], 1);
        st_cheb<128>(sm, tid, li - 4, 32 + b, a.Lb, a.x, a.XbL0);
        fl_arrive(&FL[FID(AL0, b)]);
    }

    // fc0: 2 units (rows 2b*64, (2b+1)*64)
    if (li == 12 || li == 13) {
        fl_wait(&FL[FID(AL0, b)], 8);
        st_fc<1, false>(sm, tid, 0, 2 * b + (li - 12), a.XbL0, a.Wt, a.gb0, a.mask,
                        a.gg0, a.gB0, a.gm0, a.gv0, a.h0, nullptr, nullptr, nullptr, 768, 64);
        fl_arrive(&FL[FID(AH0, b)]);
    }

    // cheb layer1: 4 units
    if (li < 4) {
        fl_wait(&FL[FID(AH0, b)], 2);
        st_cheb<64>(sm, tid, li & 1, b + 32 * (li >> 1), a.Lb, a.h0, a.XbL1);
        fl_arrive(&FL[FID(AX1, b)]);
    }

    // fc1: 4 units
    if (li >= 4 && li < 8) {
        fl_wait(&FL[FID(AX1, b)], 4);
        st_fc<2, false>(sm, tid, li - 4, b, a.XbL1, a.Wt + 49152, a.gb1, a.mask,
                        a.gg1, a.gB1, a.gm1, a.gv1, a.h1, nullptr, nullptr, nullptr, 384, 256);
        fl_arrive(&FL[FID(AH1, b)]);
    }

    // cheb layer2: 16 units (all blocks of the batch)
    fl_wait(&FL[FID(AH1, b)], 4);
    st_cheb<256>(sm, tid, li & 7, b + 32 * (li >> 3), a.Lb, a.h1, a.XbL2);
    fl_arrive(&FL[FID(AX2, b)]);

    // fc2 + pool + folded classifier: 8 units
    if (li < 8) {
        fl_wait(&FL[FID(AX2, b)], 16);
        st_fc<2, true>(sm, tid, li, b, a.XbL2, a.Wt + 147456, a.gb2, a.mask,
                       a.gg2, a.gB2, a.gm2, a.gv2, nullptr, a.Wc, a.bc, a.outc, 1536, 512);
    }
}

extern "C" void kernel_launch(void* const* d_in, const int* in_sizes, int n_in,
                              void* d_out, int out_size, void* d_ws, size_t ws_size,
                              hipStream_t stream) {
    (void)in_sizes; (void)n_in; (void)ws_size;
    float* ws = (float*)d_ws;

    MArgs a;
    a.x    = (const float*)d_in[0];
    a.A    = (const float*)d_in[1];
    a.mask = (const float*)d_in[2];
    a.eW1  = (const float*)d_in[3];
    a.eb1  = (const float*)d_in[4];
    a.eW2  = (const float*)d_in[5];
    a.eb2  = (const float*)d_in[6];
    a.W0   = (const float*)d_in[7];
    a.gb0  = (const float*)d_in[8];  a.gg0 = (const float*)d_in[9];  a.gB0 = (const float*)d_in[10];
    a.gm0  = (const float*)d_in[11]; a.gv0 = (const float*)d_in[12];
    a.W1   = (const float*)d_in[13];
    a.gb1  = (const float*)d_in[14]; a.gg1 = (const float*)d_in[15]; a.gB1 = (const float*)d_in[16];
    a.gm1  = (const float*)d_in[17]; a.gv1 = (const float*)d_in[18];
    a.W2   = (const float*)d_in[19];
    a.gb2  = (const float*)d_in[20]; a.gg2 = (const float*)d_in[21]; a.gB2 = (const float*)d_in[22];
    a.gm2  = (const float*)d_in[23]; a.gv2 = (const float*)d_in[24];
    a.fW1  = (const float*)d_in[25]; a.fb1 = (const float*)d_in[26];
    a.fW2  = (const float*)d_in[27]; a.fb2 = (const float*)d_in[28];

    a.uv    = ws + OFF_UV;
    a.ap    = ws + OFF_AP;
    a.h0    = ws + OFF_H0;
    a.h1    = ws + OFF_H1;
    a.Wc    = ws + OFF_WC;
    a.bc    = ws + OFF_BC;
    a.Lb    = (unsigned short*)(ws + OFF_LB);
    a.XbL0  = (unsigned short*)(ws + OFF_XL0);
    a.XbL1  = (unsigned short*)(ws + OFF_XL1);
    a.XbL2  = (unsigned short*)(ws + OFF_XL2);
    a.Wt    = (unsigned short*)(ws + OFF_WT);
    a.flags = (unsigned*)(ws + OFF_FL);
    a.outc  = (float*)d_out;

    hipMemsetAsync(d_out, 0, (size_t)out_size * sizeof(float), stream);
    mega<<<GRIDN, 256, 0, stream>>>(a);
}